// Round 6
// baseline (184.416 us; speedup 1.0000x reference)
//
#include <hip/hip_runtime.h>
#include <hip/hip_bf16.h>

// Problem: B=2, S=2048, D=256, H=8.
// out[b,h,s,:] = sum_{t<=s} exp( max(d2(s,t),0) / (2*gamma_h - 1e-6) ) * V[b,t,:]
// d2(s,t) = |Q_s|^2 + |K_t|^2 - 2 Q_s.K_t ; Q=p@Wq, K=p@Wk, V=e@Wv.
// Heads with equal gamma produce identical outputs -> dedupe by representative.
//
// R3: flash needs ~128 VGPRs resident Q frags; launch_bounds min-waves = 2.
// R4: unpaired TSPLIT=8 -> zero-work blocks + tail. R5: paired 256 blocks,
// uniform, but 1 block/CU = 4 waves/CU -> pure latency bound (Occ 8.4%,
// Mfma 5.7%). R6: paired TSPLIT=8 -> 512 uniform blocks, 2 blocks/CU,
// 8 waves/CU; copy_heads reads rep slab once per thread.

#define BB   2
#define SS   2048
#define DD   256
#define HH   8
#define BSR  (BB*SS)        // 4096 rows
#define TSPLIT 8

typedef __bf16 bf16_t;
typedef __bf16 bf16x8 __attribute__((ext_vector_type(8)));
typedef float  f32x4  __attribute__((ext_vector_type(4)));

static __device__ __forceinline__ f32x4 mfma16(bf16x8 a, bf16x8 b, f32x4 c) {
    return __builtin_amdgcn_mfma_f32_16x16x32_bf16(a, b, c, 0, 0, 0);
}

// ---------------------------------------------------------------------------
// K0: W transpose + bf16 hi/lo split (blocks 0..47) and q2/k2 zeroing
// (block 48). Wt[n][k] = W[k][n] so MFMA B-frags read 16B straight runs.
// ---------------------------------------------------------------------------
__global__ __launch_bounds__(256) void att_wtrans(
    const float* __restrict__ Wq, const float* __restrict__ Wk,
    const float* __restrict__ Wv,
    bf16_t* __restrict__ Wqt_h, bf16_t* __restrict__ Wqt_l,
    bf16_t* __restrict__ Wkt_h, bf16_t* __restrict__ Wkt_l,
    bf16_t* __restrict__ Wvt, float* __restrict__ q2, float* __restrict__ k2)
{
    __shared__ float tile[64][65];
    const int tid = threadIdx.x;
    if (blockIdx.x == 48) {              // zero q2/k2 (gemm accumulates atomically)
        for (int i = tid; i < BSR; i += 256) { q2[i] = 0.f; k2[i] = 0.f; }
        return;
    }
    const int mat = blockIdx.x >> 4;        // 0=Wq 1=Wk 2=Wv
    const int tl  = blockIdx.x & 15;
    const int tr  = (tl >> 2) * 64, tc = (tl & 3) * 64;
    const float* W = (mat == 0) ? Wq : ((mat == 1) ? Wk : Wv);
    const int c = tid & 63, r0 = tid >> 6;

#pragma unroll
    for (int i = 0; i < 16; ++i)
        tile[r0 + 4 * i][c] = W[(size_t)(tr + r0 + 4 * i) * DD + tc + c];
    __syncthreads();

#pragma unroll
    for (int i = 0; i < 16; ++i) {
        const int nr = r0 + 4 * i;
        const float v = tile[c][nr];            // W[tr+c][tc+nr]
        const size_t oidx = (size_t)(tc + nr) * DD + tr + c;
        if (mat == 0) {
            const bf16_t h = (bf16_t)v;
            Wqt_h[oidx] = h; Wqt_l[oidx] = (bf16_t)(v - (float)h);
        } else if (mat == 1) {
            const bf16_t h = (bf16_t)v;
            Wkt_h[oidx] = h; Wkt_l[oidx] = (bf16_t)(v - (float)h);
        } else {
            Wvt[oidx] = (bf16_t)v;
        }
    }
}

// ---------------------------------------------------------------------------
// K0b: zero only the representative-head output slabs (atomic targets).
// Reads gamma on-device, so stays general. Grid (64, B*H).
// ---------------------------------------------------------------------------
__global__ __launch_bounds__(256) void att_zero_reps(
    const float* __restrict__ gamma, float* __restrict__ out)
{
    const int h = blockIdx.y & (HH - 1);
    const int b = blockIdx.y / HH;
    int rep = 0;
    while (gamma[rep] != gamma[h]) ++rep;
    if (rep != h) return;                       // duplicate: copy kernel fills it
    float4* dst = (float4*)(out + ((size_t)b * HH + h) * SS * DD);
    const int n4 = SS * DD / 4;                 // 131072 float4
    for (int i = blockIdx.x * 256 + threadIdx.x; i < n4; i += 64 * 256)
        dst[i] = float4{0.f, 0.f, 0.f, 0.f};
}

// ---------------------------------------------------------------------------
// K1: fused QKV projection via MFMA. Block = 256 thr (4 waves), 16 rows x
// 64 n-cols (4-way n-split over grid for occupancy); wave w owns 16 cols.
// A-frags: fp32 p/e from global (L1-hot across waves), hi/lo split in-reg.
// Q/K bf16x3 split (fp32-class accuracy); V single bf16. q2/k2 via shuffle
// reduce + atomicAdd partials (arrays pre-zeroed by att_wtrans).
// ---------------------------------------------------------------------------
__global__ __launch_bounds__(256, 2) void att_gemm_qkv(
    const float* __restrict__ p, const float* __restrict__ e,
    const bf16_t* __restrict__ Wqt_h, const bf16_t* __restrict__ Wqt_l,
    const bf16_t* __restrict__ Wkt_h, const bf16_t* __restrict__ Wkt_l,
    const bf16_t* __restrict__ Wvt,
    bf16_t* __restrict__ Qh, bf16_t* __restrict__ Ql,
    bf16_t* __restrict__ Kh, bf16_t* __restrict__ Kl,
    bf16_t* __restrict__ Vt, float* __restrict__ q2, float* __restrict__ k2)
{
    __shared__ bf16_t vts[64][16];     // 32B rows (16B-aligned for b128 reads)

    const int tid  = threadIdx.x;
    const int w    = tid >> 6;
    const int lane = tid & 63;
    const int m16  = lane & 15;
    const int quad = lane >> 4;
    const int row0 = (blockIdx.x >> 2) * 16;
    const int nb   = blockIdx.x & 3;
    const int arow = row0 + m16;            // this lane's A row
    const int ncol = nb * 64 + w * 16 + m16;

    f32x4 aQ = f32x4{0.f, 0.f, 0.f, 0.f};
    f32x4 aK = f32x4{0.f, 0.f, 0.f, 0.f};
    f32x4 aV = f32x4{0.f, 0.f, 0.f, 0.f};

#pragma unroll 2
    for (int kc = 0; kc < 8; ++kc) {
        const float* pp = p + (size_t)arow * DD + kc * 32 + quad * 8;
        const float* ep = e + (size_t)arow * DD + kc * 32 + quad * 8;
        const float4 p0 = *(const float4*)pp;
        const float4 p1 = *(const float4*)(pp + 4);
        const float4 e0 = *(const float4*)ep;
        const float4 e1 = *(const float4*)(ep + 4);
        const float pa[8] = {p0.x, p0.y, p0.z, p0.w, p1.x, p1.y, p1.z, p1.w};
        const float ea[8] = {e0.x, e0.y, e0.z, e0.w, e1.x, e1.y, e1.z, e1.w};
        bf16x8 aph, apl, aeb;
#pragma unroll
        for (int j = 0; j < 8; ++j) {
            const bf16_t h = (bf16_t)pa[j];
            aph[j] = h;
            apl[j] = (bf16_t)(pa[j] - (float)h);
            aeb[j] = (bf16_t)ea[j];
        }
        const size_t wo = (size_t)ncol * DD + kc * 32 + quad * 8;
        const bf16x8 bqh = *(const bf16x8*)(Wqt_h + wo);
        const bf16x8 bql = *(const bf16x8*)(Wqt_l + wo);
        const bf16x8 bkh = *(const bf16x8*)(Wkt_h + wo);
        const bf16x8 bkl = *(const bf16x8*)(Wkt_l + wo);
        const bf16x8 bv  = *(const bf16x8*)(Wvt + wo);
        aQ = mfma16(aph, bqh, aQ);
        aQ = mfma16(apl, bqh, aQ);
        aQ = mfma16(aph, bql, aQ);
        aK = mfma16(aph, bkh, aK);
        aK = mfma16(apl, bkh, aK);
        aK = mfma16(aph, bkl, aK);
        aV = mfma16(aeb, bv, aV);
    }

    // Epilogue: stores + row-norm partials + V transpose staging.
    float sq[4], sk[4];
#pragma unroll
    for (int r = 0; r < 4; ++r) {
        const int rl = quad * 4 + r;          // C/D row = quad*4+reg
        const size_t go = (size_t)(row0 + rl) * DD + ncol;
        const float qv = aQ[r], kv = aK[r], vv = aV[r];
        const bf16_t qh_ = (bf16_t)qv; const bf16_t ql_ = (bf16_t)(qv - (float)qh_);
        const bf16_t kh_ = (bf16_t)kv; const bf16_t kl_ = (bf16_t)(kv - (float)kh_);
        Qh[go] = qh_; Ql[go] = ql_;
        Kh[go] = kh_; Kl[go] = kl_;
        sq[r] = qv * qv; sk[r] = kv * kv;
        vts[w * 16 + m16][rl] = (bf16_t)vv;
    }

#pragma unroll
    for (int r = 0; r < 4; ++r) {
        float vq = sq[r], vk = sk[r];
#pragma unroll
        for (int off = 8; off >= 1; off >>= 1) {   // sum over 16 n-cols (m16 bits)
            vq += __shfl_xor(vq, off);
            vk += __shfl_xor(vk, off);
        }
        if (m16 == 0) {
            atomicAdd(q2 + row0 + quad * 4 + r, vq);
            atomicAdd(k2 + row0 + quad * 4 + r, vk);
        }
    }

    __syncthreads();
    if (tid < 64) {
        const int bb2 = row0 >> 11, t0v = row0 & 2047;
        bf16_t* dst = Vt + ((size_t)bb2 * DD + nb * 64 + tid) * SS + t0v;
        *(uint4*)dst       = *(const uint4*)&vts[tid][0];
        *((uint4*)dst + 1) = *(const uint4*)&vts[tid][8];
    }
}

// ---------------------------------------------------------------------------
// K2: flash-style causal pass, triangle-paired for uniform load.
// Block = 256 thr (4 waves); grid (32 pairs, TSPLIT=8, B) = 512 blocks,
// 2 blocks/CU -> 8 waves/CU for latency hiding. Each block sequentially
// handles s-tiles `pair` and `63-pair` (tile counts sum to 33 -> ~4.1
// tiles/block). Q hi/lo fragments in registers; V prefetched at tile top.
// Scores: bf16x3 split MFMA. PV: bf16 MFMA. Partials accumulated into
// pre-zeroed rep-head slabs via fp32 atomics.
// ---------------------------------------------------------------------------
__global__ __launch_bounds__(256, 2) void att_flash(
    const bf16_t* __restrict__ Qh, const bf16_t* __restrict__ Ql,
    const bf16_t* __restrict__ Kh, const bf16_t* __restrict__ Kl,
    const bf16_t* __restrict__ Vt, const float* __restrict__ q2,
    const float* __restrict__ k2, const float* __restrict__ gamma,
    float* __restrict__ out)
{
    __shared__ bf16_t Pb[2][32][72];   // P double buffer, stride 72 (144B rows)

    const int tid   = threadIdx.x;
    const int pair  = blockIdx.x;      // 0..31
    const int split = blockIdx.y;
    const int b     = blockIdx.z;
    const int wave  = tid >> 6;
    const int lane  = tid & 63;
    const int m16   = lane & 15;
    const int quad  = lane >> 4;

    float g[8];
#pragma unroll
    for (int h = 0; h < 8; ++h) g[h] = gamma[h];

    int pb = 0;

    for (int half = 0; half < 2; ++half) {
        const int st = half ? (63 - pair) : pair;
        const int s0 = st * 32;

        // Q fragments -> registers (16 hi + 16 lo bf16x8 = 128 VGPRs).
        bf16x8 aQh[2][8], aQl[2][8];
#pragma unroll
        for (int mt = 0; mt < 2; ++mt)
#pragma unroll
            for (int kc = 0; kc < 8; ++kc) {
                const size_t base =
                    ((size_t)(b * SS + s0 + mt * 16 + m16)) * DD + kc * 32 + quad * 8;
                aQh[mt][kc] = *(const bf16x8*)(Qh + base);
                aQl[mt][kc] = *(const bf16x8*)(Ql + base);
            }

        float q2r[2][4];
#pragma unroll
        for (int mt = 0; mt < 2; ++mt)
#pragma unroll
            for (int r = 0; r < 4; ++r)
                q2r[mt][r] = q2[b * SS + s0 + mt * 16 + quad * 4 + r];

        const int n_tiles = (s0 + 31) / 64 + 1;   // t-tiles of 64, t0 <= s0+31

        for (int h = 0; h < HH; ++h) {
            int rep = 0;
            while (g[rep] != g[h]) ++rep;
            if (rep != h) continue;               // duplicate: copy kernel fills it
            const float cexp = 1.0f / (2.0f * g[h] - 1e-6f);

            f32x4 O[2][4];
#pragma unroll
            for (int mt = 0; mt < 2; ++mt)
#pragma unroll
                for (int nt = 0; nt < 4; ++nt)
                    O[mt][nt] = f32x4{0.f, 0.f, 0.f, 0.f};

            for (int ti = split; ti < n_tiles; ti += TSPLIT) {
                const int t0 = ti * 64;
                const int tg = t0 + wave * 16 + m16;   // this lane's t column

                // ---- V prefetch (independent of P; overlaps scores+barrier)
                bf16x8 vf[2][4];
#pragma unroll
                for (int kc2 = 0; kc2 < 2; ++kc2)
#pragma unroll
                    for (int nt = 0; nt < 4; ++nt) {
                        const int dcol = wave * 64 + nt * 16 + m16;
                        vf[kc2][nt] = *(const bf16x8*)(
                            Vt + (size_t)b * DD * SS + (size_t)dcol * SS +
                            t0 + kc2 * 32 + quad * 8);
                    }
                const float k2v = k2[b * SS + tg];

                // ---- scores: S = Qh.Kh + Ql.Kh + Qh.Kl (fp32 acc) ----
                f32x4 acc0 = f32x4{0.f, 0.f, 0.f, 0.f};
                f32x4 acc1 = f32x4{0.f, 0.f, 0.f, 0.f};
                const bf16_t* khp = Kh + ((size_t)(b * SS + tg)) * DD + quad * 8;
                const bf16_t* klp = Kl + ((size_t)(b * SS + tg)) * DD + quad * 8;
#pragma unroll
                for (int kc = 0; kc < 8; ++kc) {
                    const bf16x8 bh = *(const bf16x8*)(khp + kc * 32);
                    const bf16x8 bl = *(const bf16x8*)(klp + kc * 32);
                    acc0 = mfma16(aQh[0][kc], bh, acc0);
                    acc1 = mfma16(aQh[1][kc], bh, acc1);
                    acc0 = mfma16(aQl[0][kc], bh, acc0);
                    acc1 = mfma16(aQl[1][kc], bh, acc1);
                    acc0 = mfma16(aQh[0][kc], bl, acc0);
                    acc1 = mfma16(aQh[1][kc], bl, acc1);
                }

#pragma unroll
                for (int mt = 0; mt < 2; ++mt) {
#pragma unroll
                    for (int r = 0; r < 4; ++r) {
                        const int sl = mt * 16 + quad * 4 + r;
                        const int sg = s0 + sl;
                        const float dotv = mt ? acc1[r] : acc0[r];
                        float d2 = q2r[mt][r] + k2v - 2.0f * dotv;
                        d2 = fmaxf(d2, 0.0f);
                        const float wgt = (tg <= sg) ? __expf(cexp * d2) : 0.0f;
                        Pb[pb][sl][wave * 16 + m16] = (bf16_t)wgt;
                    }
                }
                __syncthreads();

                // ---- PV: O += P @ V (V already in registers) ----
#pragma unroll
                for (int kc2 = 0; kc2 < 2; ++kc2) {
                    const bf16x8 pa0 = *(const bf16x8*)&Pb[pb][m16][kc2 * 32 + quad * 8];
                    const bf16x8 pa1 = *(const bf16x8*)&Pb[pb][m16 + 16][kc2 * 32 + quad * 8];
#pragma unroll
                    for (int nt = 0; nt < 4; ++nt) {
                        O[0][nt] = mfma16(pa0, vf[kc2][nt], O[0][nt]);
                        O[1][nt] = mfma16(pa1, vf[kc2][nt], O[1][nt]);
                    }
                }
                pb ^= 1;
            }

            // ---- accumulate split partials into out[b][h] ----
#pragma unroll
            for (int mt = 0; mt < 2; ++mt)
#pragma unroll
                for (int nt = 0; nt < 4; ++nt)
#pragma unroll
                    for (int r = 0; r < 4; ++r) {
                        const int sl   = mt * 16 + quad * 4 + r;
                        const int dcol = wave * 64 + nt * 16 + m16;
                        atomicAdd(out + (((size_t)b * HH + h) * SS + (s0 + sl)) * DD + dcol,
                                  O[mt][nt][r]);
                    }
        }
    }
}

// ---------------------------------------------------------------------------
// K3: replicate representative-head outputs to duplicate-gamma heads.
// One thread per rep-slab float4: read once, write all duplicates.
// Grid (SS*DD/4/256, B).
// ---------------------------------------------------------------------------
__global__ __launch_bounds__(256) void att_copy_heads(
    const float* __restrict__ gamma, float* __restrict__ out)
{
    const int j = blockIdx.x * 256 + threadIdx.x;     // float4 index in a slab
    const int b = blockIdx.y;
    float4* o4 = (float4*)out + (size_t)b * HH * (SS * DD / 4);

    float g[8];
#pragma unroll
    for (int h = 0; h < 8; ++h) g[h] = gamma[h];

    float4 cached; int cached_rep = -1;
#pragma unroll
    for (int h = 1; h < HH; ++h) {
        int rep = 0;
        while (g[rep] != g[h]) ++rep;
        if (rep == h) continue;
        if (rep != cached_rep) {
            cached = o4[(size_t)rep * (SS * DD / 4) + j];
            cached_rep = rep;
        }
        o4[(size_t)h * (SS * DD / 4) + j] = cached;
    }
}

extern "C" void kernel_launch(void* const* d_in, const int* in_sizes, int n_in,
                              void* d_out, int out_size, void* d_ws, size_t ws_size,
                              hipStream_t stream) {
    (void)in_sizes; (void)n_in; (void)out_size; (void)ws_size;
    // inputs: 0=x (unused), 1=e, 2=p, 3=W_q, 4=W_k, 5=W_v, 6=gamma
    const float* e     = (const float*)d_in[1];
    const float* p     = (const float*)d_in[2];
    const float* Wq    = (const float*)d_in[3];
    const float* Wk    = (const float*)d_in[4];
    const float* Wv    = (const float*)d_in[5];
    const float* gamma = (const float*)d_in[6];

    const size_t NROW = (size_t)BSR * DD;   // 1048576 elements
    bf16_t* Qh = (bf16_t*)d_ws;
    bf16_t* Ql = Qh + NROW;
    bf16_t* Kh = Ql + NROW;
    bf16_t* Kl = Kh + NROW;
    bf16_t* Vt = Kl + NROW;                 // [B][D][S]
    float*  q2 = (float*)(Vt + NROW);
    float*  k2 = q2 + BSR;
    bf16_t* Wqt_h = (bf16_t*)(k2 + BSR);    // transposed weights [n][k]
    bf16_t* Wqt_l = Wqt_h + DD * DD;
    bf16_t* Wkt_h = Wqt_l + DD * DD;
    bf16_t* Wkt_l = Wkt_h + DD * DD;
    bf16_t* Wvt   = Wkt_l + DD * DD;

    float* out = (float*)d_out;

    att_wtrans<<<dim3(49), dim3(256), 0, stream>>>(
        Wq, Wk, Wv, Wqt_h, Wqt_l, Wkt_h, Wkt_l, Wvt, q2, k2);

    att_zero_reps<<<dim3(64, BB * HH), dim3(256), 0, stream>>>(gamma, out);

    att_gemm_qkv<<<dim3((BSR / 16) * 4), dim3(256), 0, stream>>>(
        p, e, Wqt_h, Wqt_l, Wkt_h, Wkt_l, Wvt, Qh, Ql, Kh, Kl, Vt, q2, k2);

    att_flash<<<dim3(32, TSPLIT, BB), dim3(256), 0, stream>>>(
        Qh, Ql, Kh, Kl, Vt, q2, k2, gamma, out);

    att_copy_heads<<<dim3(SS * DD / 4 / 256, BB), dim3(256), 0, stream>>>(
        gamma, out);
}

// Round 7
// 150.039 us; speedup vs baseline: 1.2291x; 1.2291x over previous
//
#include <hip/hip_runtime.h>
#include <hip/hip_bf16.h>

// Problem: B=2, S=2048, D=256, H=8.
// out[b,h,s,:] = sum_{t<=s} exp( max(d2(s,t),0) / (2*gamma_h - 1e-6) ) * V[b,t,:]
// d2(s,t) = |Q_s|^2 + |K_t|^2 - 2 Q_s.K_t ; Q=p@Wq, K=p@Wk, V=e@Wv.
// Heads with equal gamma produce identical outputs -> dedupe by representative.
//
// R3: flash needs ~128 VGPRs resident Q frags; launch_bounds min-waves = 2.
// R5/R6: occupancy moves didn't move MfmaUtil (~5%) -> bottleneck was the
// 16-way-scattered fragment loads (lane m16 strides 512B/4KB => ~1536
// transactions/tile/CU). R7: pre-swizzle ALL MFMA operands fragment-major
// (QF/KF/VF/WF) so every hot b128 load is one contiguous 1KB transaction.

#define BB   2
#define SS   2048
#define DD   256
#define HH   8
#define BSR  (BB*SS)        // 4096 rows
#define TSPLIT 4

typedef __bf16 bf16_t;
typedef __bf16 bf16x8 __attribute__((ext_vector_type(8)));
typedef float  f32x4  __attribute__((ext_vector_type(4)));

static __device__ __forceinline__ f32x4 mfma16(bf16x8 a, bf16x8 b, f32x4 c) {
    return __builtin_amdgcn_mfma_f32_16x16x32_bf16(a, b, c, 0, 0, 0);
}

// ---------------------------------------------------------------------------
// K0: W -> fragment-major WF (hi/lo split), plus q2/k2 zeroing (block 48).
// WF chunk (g16 in [0,16), kc in [0,8)) holds 512 elems at ((g16*8+kc)*512):
// position u*8+j = W^T[n = g16*16 + (u&15)][k = kc*32 + (u>>4)*8 + j].
// gemm's B-frag load is then base + lane*8 : contiguous 1KB per wave.
// ---------------------------------------------------------------------------
__global__ __launch_bounds__(256) void att_wtrans(
    const float* __restrict__ Wq, const float* __restrict__ Wk,
    const float* __restrict__ Wv,
    bf16_t* __restrict__ WFq_h, bf16_t* __restrict__ WFq_l,
    bf16_t* __restrict__ WFk_h, bf16_t* __restrict__ WFk_l,
    bf16_t* __restrict__ WFv, float* __restrict__ q2, float* __restrict__ k2)
{
    __shared__ float tT[64][68];    // [n_local][k_local], pad 68
    const int tid = threadIdx.x;
    if (blockIdx.x == 48) {         // zero q2/k2 (gemm accumulates atomically)
        for (int i = tid; i < BSR; i += 256) { q2[i] = 0.f; k2[i] = 0.f; }
        return;
    }
    const int mat = blockIdx.x >> 4;        // 0=Wq 1=Wk 2=Wv
    const int tl  = blockIdx.x & 15;
    const int tr  = (tl >> 2) * 64, tc = (tl & 3) * 64;  // k-range, n-range
    const float* W = (mat == 0) ? Wq : ((mat == 1) ? Wk : Wv);

    // load W[k][n] tile rows coalesced, scatter transposed into LDS
#pragma unroll
    for (int i = 0; i < 4; ++i) {
        const int fidx = i * 256 + tid;     // [0,1024) float4 units
        const int r  = fidx >> 4;           // k_local
        const int c4 = fidx & 15;           // n_local/4
        const float4 v = *(const float4*)(W + (size_t)(tr + r) * DD + tc + c4 * 4);
        tT[c4 * 4 + 0][r] = v.x; tT[c4 * 4 + 1][r] = v.y;
        tT[c4 * 4 + 2][r] = v.z; tT[c4 * 4 + 3][r] = v.w;
    }
    __syncthreads();

#pragma unroll
    for (int i = 0; i < 2; ++i) {
        const int uidx  = i * 256 + tid;    // [0,512) 16B units
        const int chunk = uidx >> 6;        // kc_l(2) x c16(4)
        const int kc_l  = chunk >> 2, c16 = chunk & 3;
        const int u = uidx & 63, m16 = u & 15, quad = u >> 4;
        const float* src = &tT[c16 * 16 + m16][kc_l * 32 + quad * 8];
        const float4 a = *(const float4*)src;
        const float4 bq = *(const float4*)(src + 4);
        const float f[8] = {a.x, a.y, a.z, a.w, bq.x, bq.y, bq.z, bq.w};
        bf16x8 hi, lo;
#pragma unroll
        for (int j = 0; j < 8; ++j) {
            const bf16_t h = (bf16_t)f[j];
            hi[j] = h; lo[j] = (bf16_t)(f[j] - (float)h);
        }
        const int g16 = (tc >> 4) + c16;
        const int kcg = (tr >> 5) + kc_l;
        const size_t off = ((size_t)(g16 * 8 + kcg)) * 512 + (size_t)u * 8;
        if (mat == 0)      { *(bf16x8*)(WFq_h + off) = hi; *(bf16x8*)(WFq_l + off) = lo; }
        else if (mat == 1) { *(bf16x8*)(WFk_h + off) = hi; *(bf16x8*)(WFk_l + off) = lo; }
        else               { *(bf16x8*)(WFv + off)  = hi; }
    }
}

// ---------------------------------------------------------------------------
// K0b: zero only the representative-head output slabs (atomic targets).
// ---------------------------------------------------------------------------
__global__ __launch_bounds__(256) void att_zero_reps(
    const float* __restrict__ gamma, float* __restrict__ out)
{
    const int h = blockIdx.y & (HH - 1);
    const int b = blockIdx.y / HH;
    int rep = 0;
    while (gamma[rep] != gamma[h]) ++rep;
    if (rep != h) return;
    float4* dst = (float4*)(out + ((size_t)b * HH + h) * SS * DD);
    const int n4 = SS * DD / 4;
    for (int i = blockIdx.x * 256 + threadIdx.x; i < n4; i += 64 * 256)
        dst[i] = float4{0.f, 0.f, 0.f, 0.f};
}

// ---------------------------------------------------------------------------
// K1: fused QKV projection via MFMA. Block = 256 thr, 16 rows x 64 n-cols
// (4-way n-split in grid). p/e staged through LDS (coalesced global reads);
// W read fragment-major from WF (contiguous 1KB per wave-load).
// Q/K bf16x3 split; V single bf16. q2/k2 via shuffle + atomicAdd partials.
// ---------------------------------------------------------------------------
__global__ __launch_bounds__(256, 2) void att_gemm_qkv(
    const float* __restrict__ p, const float* __restrict__ e,
    const bf16_t* __restrict__ WFq_h, const bf16_t* __restrict__ WFq_l,
    const bf16_t* __restrict__ WFk_h, const bf16_t* __restrict__ WFk_l,
    const bf16_t* __restrict__ WFv,
    bf16_t* __restrict__ Qh, bf16_t* __restrict__ Ql,
    bf16_t* __restrict__ Kh, bf16_t* __restrict__ Kl,
    bf16_t* __restrict__ Vt, float* __restrict__ q2, float* __restrict__ k2)
{
    __shared__ float pL[16][264];
    __shared__ float eL[16][264];
    __shared__ bf16_t vts[64][16];

    const int tid  = threadIdx.x;
    const int w    = tid >> 6;
    const int lane = tid & 63;
    const int m16  = lane & 15;
    const int quad = lane >> 4;
    const int row0 = (blockIdx.x >> 2) * 16;
    const int nb   = blockIdx.x & 3;
    const int ncol = nb * 64 + w * 16 + m16;

    // stage p/e tiles (16 rows x 256 cols), coalesced
#pragma unroll
    for (int i = 0; i < 4; ++i) {
        const int fidx = i * 256 + tid;     // [0,1024) float4
        const int r  = fidx >> 6;
        const int c4 = fidx & 63;
        const float4 pv = *(const float4*)(p + (size_t)(row0 + r) * DD + c4 * 4);
        const float4 ev = *(const float4*)(e + (size_t)(row0 + r) * DD + c4 * 4);
        *(float4*)&pL[r][c4 * 4] = pv;
        *(float4*)&eL[r][c4 * 4] = ev;
    }
    __syncthreads();

    f32x4 aQ = f32x4{0.f, 0.f, 0.f, 0.f};
    f32x4 aK = f32x4{0.f, 0.f, 0.f, 0.f};
    f32x4 aV = f32x4{0.f, 0.f, 0.f, 0.f};

#pragma unroll 2
    for (int kc = 0; kc < 8; ++kc) {
        const float* ps = &pL[m16][kc * 32 + quad * 8];
        const float* es = &eL[m16][kc * 32 + quad * 8];
        const float4 p0 = *(const float4*)ps;
        const float4 p1 = *(const float4*)(ps + 4);
        const float4 e0 = *(const float4*)es;
        const float4 e1 = *(const float4*)(es + 4);
        const float pa[8] = {p0.x, p0.y, p0.z, p0.w, p1.x, p1.y, p1.z, p1.w};
        const float ea[8] = {e0.x, e0.y, e0.z, e0.w, e1.x, e1.y, e1.z, e1.w};
        bf16x8 aph, apl, aeb;
#pragma unroll
        for (int j = 0; j < 8; ++j) {
            const bf16_t h = (bf16_t)pa[j];
            aph[j] = h;
            apl[j] = (bf16_t)(pa[j] - (float)h);
            aeb[j] = (bf16_t)ea[j];
        }
        const size_t wo = ((size_t)((nb * 4 + w) * 8 + kc)) * 512 + (size_t)lane * 8;
        const bf16x8 bqh = *(const bf16x8*)(WFq_h + wo);
        const bf16x8 bql = *(const bf16x8*)(WFq_l + wo);
        const bf16x8 bkh = *(const bf16x8*)(WFk_h + wo);
        const bf16x8 bkl = *(const bf16x8*)(WFk_l + wo);
        const bf16x8 bv  = *(const bf16x8*)(WFv + wo);
        aQ = mfma16(aph, bqh, aQ);
        aQ = mfma16(apl, bqh, aQ);
        aQ = mfma16(aph, bql, aQ);
        aK = mfma16(aph, bkh, aK);
        aK = mfma16(apl, bkh, aK);
        aK = mfma16(aph, bkl, aK);
        aV = mfma16(aeb, bv, aV);
    }

    // Epilogue: stores + row-norm partials + V transpose staging.
    float sq[4], sk[4];
#pragma unroll
    for (int r = 0; r < 4; ++r) {
        const int rl = quad * 4 + r;          // C/D row = quad*4+reg
        const size_t go = (size_t)(row0 + rl) * DD + ncol;
        const float qv = aQ[r], kv = aK[r], vv = aV[r];
        const bf16_t qh_ = (bf16_t)qv; const bf16_t ql_ = (bf16_t)(qv - (float)qh_);
        const bf16_t kh_ = (bf16_t)kv; const bf16_t kl_ = (bf16_t)(kv - (float)kh_);
        Qh[go] = qh_; Ql[go] = ql_;
        Kh[go] = kh_; Kl[go] = kl_;
        sq[r] = qv * qv; sk[r] = kv * kv;
        vts[w * 16 + m16][rl] = (bf16_t)vv;
    }

#pragma unroll
    for (int r = 0; r < 4; ++r) {
        float vq = sq[r], vk = sk[r];
#pragma unroll
        for (int off = 8; off >= 1; off >>= 1) {
            vq += __shfl_xor(vq, off);
            vk += __shfl_xor(vk, off);
        }
        if (m16 == 0) {
            atomicAdd(q2 + row0 + quad * 4 + r, vq);
            atomicAdd(k2 + row0 + quad * 4 + r, vk);
        }
    }

    __syncthreads();
    if (tid < 64) {
        const int bb2 = row0 >> 11, t0v = row0 & 2047;
        bf16_t* dst = Vt + ((size_t)bb2 * DD + nb * 64 + tid) * SS + t0v;
        *(uint4*)dst       = *(const uint4*)&vts[tid][0];
        *((uint4*)dst + 1) = *(const uint4*)&vts[tid][8];
    }
}

// ---------------------------------------------------------------------------
// K1.5: repack Q/K (hi,lo) and V into fragment-major QF/KF/VF so flash's
// per-wave b128 loads are contiguous 1KB runs.
// KF tile (b,tt): 16384 elems; chunk (w,kc): u*8+j = K[tt*64+w*16+(u&15)]
//                                                    [kc*32+(u>>4)*8+j]
// QF s-tile (b,st32): 8192 elems; chunk (mt,kc) likewise.
// VF tile (b,tt): chunk (w,kc2,nt): u*8+j = V[t=tt*64+kc2*32+(u>>4)*8+j]
//                                            [d=w*64+nt*16+(u&15)] (from Vt).
// Grid (32 tt, 5 parts, B).
// ---------------------------------------------------------------------------
__global__ __launch_bounds__(256) void att_repack(
    const bf16_t* __restrict__ Qh, const bf16_t* __restrict__ Ql,
    const bf16_t* __restrict__ Kh, const bf16_t* __restrict__ Kl,
    const bf16_t* __restrict__ Vt,
    bf16_t* __restrict__ QFh, bf16_t* __restrict__ QFl,
    bf16_t* __restrict__ KFh, bf16_t* __restrict__ KFl,
    bf16_t* __restrict__ VF)
{
    __shared__ bf16_t rowT[64][264];   // [t_local][d] for Q/K parts
    __shared__ bf16_t vT[256][72];     // [d][t_local] for V

    const int tid  = threadIdx.x;
    const int tt   = blockIdx.x;       // [0,32) 64-row t-tiles
    const int part = blockIdx.y;       // 0=Kh 1=Kl 2=Qh 3=Ql 4=V
    const int b    = blockIdx.z;

    if (part < 4) {
        const bf16_t* src = (part == 0) ? Kh : (part == 1) ? Kl
                          : (part == 2) ? Qh : Ql;
#pragma unroll
        for (int i = 0; i < 8; ++i) {
            const int off = (i * 256 + tid) * 8;
            const int r = off >> 8, c = off & 255;
            *(bf16x8*)&rowT[r][c] =
                *(const bf16x8*)(src + ((size_t)(b * SS + tt * 64 + r)) * DD + c);
        }
        __syncthreads();
        if (part < 2) {
            bf16_t* dst = (part == 0) ? KFh : KFl;
#pragma unroll
            for (int i = 0; i < 8; ++i) {
                const int g = i * 256 + tid;
                const int chunk = g >> 6, u = g & 63;
                const int w_ = chunk >> 3, kc = chunk & 7;
                const bf16x8 v = *(const bf16x8*)
                    &rowT[w_ * 16 + (u & 15)][kc * 32 + (u >> 4) * 8];
                *(bf16x8*)(dst + ((size_t)(b * 32 + tt)) * 16384 + (size_t)g * 8) = v;
            }
        } else {
            bf16_t* dst = (part == 2) ? QFh : QFl;
#pragma unroll
            for (int i = 0; i < 8; ++i) {
                const int g = i * 256 + tid;
                const int chunk = g >> 6, u = g & 63;
                const int sub = chunk >> 4, mt = (chunk >> 3) & 1, kc = chunk & 7;
                const bf16x8 v = *(const bf16x8*)
                    &rowT[sub * 32 + mt * 16 + (u & 15)][kc * 32 + (u >> 4) * 8];
                const int st = tt * 2 + sub;
                *(bf16x8*)(dst + ((size_t)(b * 64 + st)) * 8192
                               + (size_t)(mt * 8 + kc) * 512 + (size_t)u * 8) = v;
            }
        }
    } else {
#pragma unroll
        for (int i = 0; i < 8; ++i) {
            const int off = (i * 256 + tid) * 8;
            const int d = off >> 6, tcol = off & 63;
            *(bf16x8*)&vT[d][tcol] =
                *(const bf16x8*)(Vt + ((size_t)(b * DD + d)) * SS + tt * 64 + tcol);
        }
        __syncthreads();
#pragma unroll
        for (int i = 0; i < 8; ++i) {
            const int g = i * 256 + tid;
            const int chunk = g >> 6, u = g & 63;
            const int w_ = chunk >> 3, kc2 = (chunk >> 2) & 1, nt = chunk & 3;
            const bf16x8 v = *(const bf16x8*)
                &vT[w_ * 64 + nt * 16 + (u & 15)][kc2 * 32 + (u >> 4) * 8];
            *(bf16x8*)(VF + ((size_t)(b * 32 + tt)) * 16384 + (size_t)g * 8) = v;
        }
    }
}

// ---------------------------------------------------------------------------
// K2: flash-style causal pass, triangle-paired, fragment-major operands.
// Block = 256 thr (4 waves); grid (32 pairs, TSPLIT=4, B) = 256 blocks.
// All hot loads (Q at half-top; K hi/lo + V per tile) are contiguous 1KB
// b128 runs. Scores: bf16x3 split MFMA. PV: bf16 MFMA. Partials -> atomics.
// ---------------------------------------------------------------------------
__global__ __launch_bounds__(256, 2) void att_flash(
    const bf16_t* __restrict__ QFh, const bf16_t* __restrict__ QFl,
    const bf16_t* __restrict__ KFh, const bf16_t* __restrict__ KFl,
    const bf16_t* __restrict__ VF, const float* __restrict__ q2,
    const float* __restrict__ k2, const float* __restrict__ gamma,
    float* __restrict__ out)
{
    __shared__ bf16_t Pb[2][32][72];

    const int tid   = threadIdx.x;
    const int pair  = blockIdx.x;      // 0..31
    const int split = blockIdx.y;
    const int b     = blockIdx.z;
    const int wave  = tid >> 6;
    const int lane  = tid & 63;
    const int m16   = lane & 15;
    const int quad  = lane >> 4;

    float g[8];
#pragma unroll
    for (int h = 0; h < 8; ++h) g[h] = gamma[h];

    int pb = 0;

    for (int half = 0; half < 2; ++half) {
        const int st = half ? (63 - pair) : pair;
        const int s0 = st * 32;

        // Q fragments -> registers, contiguous chunk loads.
        bf16x8 aQh[2][8], aQl[2][8];
        const size_t qtile = ((size_t)(b * 64 + st)) * 8192 + (size_t)lane * 8;
#pragma unroll
        for (int mt = 0; mt < 2; ++mt)
#pragma unroll
            for (int kc = 0; kc < 8; ++kc) {
                const size_t base = qtile + (size_t)(mt * 8 + kc) * 512;
                aQh[mt][kc] = *(const bf16x8*)(QFh + base);
                aQl[mt][kc] = *(const bf16x8*)(QFl + base);
            }

        float q2r[2][4];
#pragma unroll
        for (int mt = 0; mt < 2; ++mt)
#pragma unroll
            for (int r = 0; r < 4; ++r)
                q2r[mt][r] = q2[b * SS + s0 + mt * 16 + quad * 4 + r];

        const int n_tiles = (s0 + 31) / 64 + 1;

        for (int h = 0; h < HH; ++h) {
            int rep = 0;
            while (g[rep] != g[h]) ++rep;
            if (rep != h) continue;
            const float cexp = 1.0f / (2.0f * g[h] - 1e-6f);

            f32x4 O[2][4];
#pragma unroll
            for (int mt = 0; mt < 2; ++mt)
#pragma unroll
                for (int nt = 0; nt < 4; ++nt)
                    O[mt][nt] = f32x4{0.f, 0.f, 0.f, 0.f};

            for (int ti = split; ti < n_tiles; ti += TSPLIT) {
                const int t0 = ti * 64;
                const int tg = t0 + wave * 16 + m16;
                const size_t tile = ((size_t)(b * 32 + ti)) * 16384
                                  + (size_t)wave * 4096 + (size_t)lane * 8;

                // V prefetch (contiguous chunks; overlaps scores+barrier)
                bf16x8 vf[2][4];
#pragma unroll
                for (int kc2 = 0; kc2 < 2; ++kc2)
#pragma unroll
                    for (int nt = 0; nt < 4; ++nt)
                        vf[kc2][nt] = *(const bf16x8*)(
                            VF + tile + (size_t)(kc2 * 4 + nt) * 512);
                const float k2v = k2[b * SS + tg];

                // scores: S = Qh.Kh + Ql.Kh + Qh.Kl (fp32 acc)
                f32x4 acc0 = f32x4{0.f, 0.f, 0.f, 0.f};
                f32x4 acc1 = f32x4{0.f, 0.f, 0.f, 0.f};
#pragma unroll
                for (int kc = 0; kc < 8; ++kc) {
                    const bf16x8 bh = *(const bf16x8*)(KFh + tile + (size_t)kc * 512);
                    const bf16x8 bl = *(const bf16x8*)(KFl + tile + (size_t)kc * 512);
                    acc0 = mfma16(aQh[0][kc], bh, acc0);
                    acc1 = mfma16(aQh[1][kc], bh, acc1);
                    acc0 = mfma16(aQl[0][kc], bh, acc0);
                    acc1 = mfma16(aQl[1][kc], bh, acc1);
                    acc0 = mfma16(aQh[0][kc], bl, acc0);
                    acc1 = mfma16(aQh[1][kc], bl, acc1);
                }

#pragma unroll
                for (int mt = 0; mt < 2; ++mt) {
#pragma unroll
                    for (int r = 0; r < 4; ++r) {
                        const int sl = mt * 16 + quad * 4 + r;
                        const int sg = s0 + sl;
                        const float dotv = mt ? acc1[r] : acc0[r];
                        float d2 = q2r[mt][r] + k2v - 2.0f * dotv;
                        d2 = fmaxf(d2, 0.0f);
                        const float wgt = (tg <= sg) ? __expf(cexp * d2) : 0.0f;
                        Pb[pb][sl][wave * 16 + m16] = (bf16_t)wgt;
                    }
                }
                __syncthreads();

                // PV: O += P @ V (V already in registers)
#pragma unroll
                for (int kc2 = 0; kc2 < 2; ++kc2) {
                    const bf16x8 pa0 = *(const bf16x8*)&Pb[pb][m16][kc2 * 32 + quad * 8];
                    const bf16x8 pa1 = *(const bf16x8*)&Pb[pb][m16 + 16][kc2 * 32 + quad * 8];
#pragma unroll
                    for (int nt = 0; nt < 4; ++nt) {
                        O[0][nt] = mfma16(pa0, vf[kc2][nt], O[0][nt]);
                        O[1][nt] = mfma16(pa1, vf[kc2][nt], O[1][nt]);
                    }
                }
                pb ^= 1;
            }

            // accumulate split partials into out[b][h]
#pragma unroll
            for (int mt = 0; mt < 2; ++mt)
#pragma unroll
                for (int nt = 0; nt < 4; ++nt)
#pragma unroll
                    for (int r = 0; r < 4; ++r) {
                        const int sl   = mt * 16 + quad * 4 + r;
                        const int dcol = wave * 64 + nt * 16 + m16;
                        atomicAdd(out + (((size_t)b * HH + h) * SS + (s0 + sl)) * DD + dcol,
                                  O[mt][nt][r]);
                    }
        }
    }
}

// ---------------------------------------------------------------------------
// K3: replicate representative-head outputs to duplicate-gamma heads.
// ---------------------------------------------------------------------------
__global__ __launch_bounds__(256) void att_copy_heads(
    const float* __restrict__ gamma, float* __restrict__ out)
{
    const int j = blockIdx.x * 256 + threadIdx.x;
    const int b = blockIdx.y;
    float4* o4 = (float4*)out + (size_t)b * HH * (SS * DD / 4);

    float g[8];
#pragma unroll
    for (int h = 0; h < 8; ++h) g[h] = gamma[h];

    float4 cached; int cached_rep = -1;
#pragma unroll
    for (int h = 1; h < HH; ++h) {
        int rep = 0;
        while (g[rep] != g[h]) ++rep;
        if (rep == h) continue;
        if (rep != cached_rep) {
            cached = o4[(size_t)rep * (SS * DD / 4) + j];
            cached_rep = rep;
        }
        o4[(size_t)h * (SS * DD / 4) + j] = cached;
    }
}

extern "C" void kernel_launch(void* const* d_in, const int* in_sizes, int n_in,
                              void* d_out, int out_size, void* d_ws, size_t ws_size,
                              hipStream_t stream) {
    (void)in_sizes; (void)n_in; (void)out_size; (void)ws_size;
    // inputs: 0=x (unused), 1=e, 2=p, 3=W_q, 4=W_k, 5=W_v, 6=gamma
    const float* e     = (const float*)d_in[1];
    const float* p     = (const float*)d_in[2];
    const float* Wq    = (const float*)d_in[3];
    const float* Wk    = (const float*)d_in[4];
    const float* Wv    = (const float*)d_in[5];
    const float* gamma = (const float*)d_in[6];

    const size_t NROW = (size_t)BSR * DD;   // 1048576 elements
    bf16_t* Qh = (bf16_t*)d_ws;
    bf16_t* Ql = Qh + NROW;
    bf16_t* Kh = Ql + NROW;
    bf16_t* Kl = Kh + NROW;
    bf16_t* Vt = Kl + NROW;                 // [B][D][S]
    float*  q2 = (float*)(Vt + NROW);
    float*  k2 = q2 + BSR;
    bf16_t* WFq_h = (bf16_t*)(k2 + BSR);    // fragment-major weights
    bf16_t* WFq_l = WFq_h + DD * DD;
    bf16_t* WFk_h = WFq_l + DD * DD;
    bf16_t* WFk_l = WFk_h + DD * DD;
    bf16_t* WFv   = WFk_l + DD * DD;
    bf16_t* QFh   = WFv + DD * DD;          // fragment-major Q/K/V
    bf16_t* QFl   = QFh + NROW;
    bf16_t* KFh   = QFl + NROW;
    bf16_t* KFl   = KFh + NROW;
    bf16_t* VF    = KFl + NROW;

    float* out = (float*)d_out;

    att_wtrans<<<dim3(49), dim3(256), 0, stream>>>(
        Wq, Wk, Wv, WFq_h, WFq_l, WFk_h, WFk_l, WFv, q2, k2);

    att_zero_reps<<<dim3(64, BB * HH), dim3(256), 0, stream>>>(gamma, out);

    att_gemm_qkv<<<dim3((BSR / 16) * 4), dim3(256), 0, stream>>>(
        p, e, WFq_h, WFq_l, WFk_h, WFk_l, WFv, Qh, Ql, Kh, Kl, Vt, q2, k2);

    att_repack<<<dim3(32, 5, BB), dim3(256), 0, stream>>>(
        Qh, Ql, Kh, Kl, Vt, QFh, QFl, KFh, KFl, VF);

    att_flash<<<dim3(32, TSPLIT, BB), dim3(256), 0, stream>>>(
        QFh, QFl, KFh, KFl, VF, q2, k2, gamma, out);

    att_copy_heads<<<dim3(SS * DD / 4 / 256, BB), dim3(256), 0, stream>>>(
        gamma, out);
}